// Round 1
// 341.986 us; speedup vs baseline: 1.2202x; 1.2202x over previous
//
#include <hip/hip_runtime.h>
#include <hip/hip_bf16.h>
#include <cstdint>

#define NEG  (-1e30f)
#define VSZ  256      // vocab size (fixed for this problem)
#define TCAP 2048     // >= T = 2000 (fallback path)
#define LN2F 0.6931471805599453f

static __device__ __forceinline__ float    uifu(unsigned u) { return __uint_as_float(u); }
static __device__ __forceinline__ unsigned f2bf(float f) {   // f >= 0, finite; RTE
    unsigned u = __float_as_uint(f);
    return (u + 0x7fffu + ((u >> 16) & 1u)) >> 16;
}

// ---------------------------------------------------------------------------
// Prep: one wave per (b,t) row. Computes lse, then writes
//   po[row][j]  = bf16( exp(logit[tg[j]] - lse) )   j in [0,256)  (odd states)
//   pbf[row]    = f32 ( exp(logit[0]     - lse) )                 (blank)
// ---------------------------------------------------------------------------
__global__ __launch_bounds__(256) void prep6(const float* __restrict__ logits,
                                             const int* __restrict__ targets,
                                             unsigned short* __restrict__ po,
                                             float* __restrict__ pbf,
                                             int T, int S) {
    const int b    = blockIdx.y;
    const int lane = threadIdx.x & 63;
    const int wv   = threadIdx.x >> 6;
    const int rt   = blockIdx.x * 4 + wv;
    if (rt >= T) return;
    const size_t row = (size_t)b * T + rt;
    __shared__ float ldsrow[4][VSZ];

    const float4* p = (const float4*)(logits + row * VSZ);
    float4 x = p[lane];
    ((float4*)&ldsrow[wv][0])[lane] = x;

    float m = fmaxf(fmaxf(x.x, x.y), fmaxf(x.z, x.w));
    #pragma unroll
    for (int off = 32; off; off >>= 1) m = fmaxf(m, __shfl_xor(m, off, 64));
    float s = __expf(x.x - m) + __expf(x.y - m) + __expf(x.z - m) + __expf(x.w - m);
    #pragma unroll
    for (int off = 32; off; off >>= 1) s += __shfl_xor(s, off, 64);
    float lse = m + __logf(s);

    const int* tg = targets + (size_t)b * S;
    const int c0 = 4 * lane;
    float pr0 = 0.f, pr1 = 0.f, pr2 = 0.f, pr3 = 0.f;
    if (c0     < S) pr0 = __expf(ldsrow[wv][tg[c0]]     - lse);
    if (c0 + 1 < S) pr1 = __expf(ldsrow[wv][tg[c0 + 1]] - lse);
    if (c0 + 2 < S) pr2 = __expf(ldsrow[wv][tg[c0 + 2]] - lse);
    if (c0 + 3 < S) pr3 = __expf(ldsrow[wv][tg[c0 + 3]] - lse);

    uint2 st;
    st.x = f2bf(pr0) | (f2bf(pr1) << 16);
    st.y = f2bf(pr2) | (f2bf(pr3) << 16);
    ((uint2*)(po + row * VSZ))[lane] = st;
    if (lane == 0) pbf[row] = __expf(x.x - lse);
}

// ---------------------------------------------------------------------------
// Scan v9: forward/backward split (2 waves per block, half the serial depth
// each, combined via total = sum_s alpha_{m-1}[s] * beta_{m-1}[s]) with
// double-buffered LDS staging through global_load_lds DMA (counted vmcnt),
// DPP wave_shr1/wave_shl1 for cross-lane neighbor values, v_readlane for the
// per-step blank-prob broadcast. Same per-thread pow2-renorm numerics as v8.
// ---------------------------------------------------------------------------
typedef __attribute__((address_space(1))) unsigned int g1u_t;
typedef __attribute__((address_space(3))) unsigned int l3u_t;

static __device__ __forceinline__ void dma16(const void* g, void* l) {
    // global->LDS DMA, 16B per lane; LDS dest = wave-uniform base + lane*16.
    // Int casts: generic global value == AS1 value; low 32b of a generic LDS
    // pointer == AS3 offset (CK's amd_direct_load pattern).
    __builtin_amdgcn_global_load_lds((g1u_t*)(uintptr_t)g,
                                     (l3u_t*)(unsigned int)(uintptr_t)l, 16, 0, 0);
}
static __device__ __forceinline__ float dpp_shr1_f(float v) {   // lane i <- i-1, lane0 -> 0
    return __int_as_float(__builtin_amdgcn_update_dpp(0, __float_as_int(v), 0x138, 0xf, 0xf, true));
}
static __device__ __forceinline__ float dpp_shl1_f(float v) {   // lane i <- i+1, lane63 -> 0
    return __int_as_float(__builtin_amdgcn_update_dpp(0, __float_as_int(v), 0x130, 0xf, 0xf, true));
}
static __device__ __forceinline__ int dpp_shr1_i(int v) {
    return __builtin_amdgcn_update_dpp(0, v, 0x138, 0xf, 0xf, true);
}
static __device__ __forceinline__ int dpp_shl1_i(int v) {
    return __builtin_amdgcn_update_dpp(0, v, 0x130, 0xf, 0xf, true);
}
static __device__ __forceinline__ float rdlane(float v, int lane) {
    return __int_as_float(__builtin_amdgcn_readlane(__float_as_int(v), lane));
}

// W = 0: forward alpha over frames [0, lenD). W = 1: backward beta consuming
// frames len-1 .. len-lenD (step t maps to frame lm1 - t).
template<int W>
static __device__ __forceinline__ void scan_dir(const unsigned short* __restrict__ po_b,
                                                const float* __restrict__ pbr,
                                                unsigned short* r0, unsigned short* r1,
                                                int lenD, int lm1, int i,
                                                float m1, float m3, float m5, float m7, float n7,
                                                float A[8], int& E) {
    const int  lhalf = i & 31;
    const bool hi    = (i >= 32);
    float dscale = 1.f;
    unsigned short* rcur = r0;
    unsigned short* rnxt = r1;

#define ROWOF(t_) (W ? max(lm1 - (t_), 0) : min((t_), lm1))

    // prologue: stage steps 0..31 into buffer 0 (16 pair-DMAs, 2 rows each)
    #pragma unroll
    for (int u = 0; u < 32; u += 2) {
        const int rA = ROWOF(u), rB = ROWOF(u + 1);
        dma16(po_b + (size_t)(hi ? rB : rA) * VSZ + 8 * lhalf, rcur + (size_t)u * VSZ);
    }
    float pbv = pbr[ROWOF(lhalf)];   // lane q holds blank prob of step q

    int t0 = 0;
    const int nsup = (lenD + 31) >> 5;
    for (int sl = 0; sl < nsup; ++sl) {
        float pn = pbr[ROWOF(t0 + 32 + lhalf)];   // blanks for next window
        #pragma unroll
        for (int h = 0; h < 4; ++h) {
            // rows for steps t0+8h..t0+8h+7 were staged one superloop ago with
            // >=12 of our DMAs issued after them; vmcnt(8) leaves margin 4.
            asm volatile("s_waitcnt vmcnt(8)" ::: "memory");
            #pragma unroll
            for (int v = 0; v < 8; ++v) {
                const int u = h * 8 + v;
                const int t = t0 + u;
                uint2 x = *(const uint2*)(rcur + (size_t)u * VSZ + 4 * i);
                float pb = rdlane(pbv, u);
                if (t < lenD) {
                    float pA = uifu(x.x << 16);
                    float pB = uifu(x.x & 0xffff0000u);
                    float pC = uifu(x.y << 16);
                    float pD = uifu(x.y & 0xffff0000u);
                    if (W == 0) {
                        float hs = dpp_shr1_f(A[7]) * dscale;          // old A7 of lane i-1
                        float s7 = fmaf(m7, A[5], A[6]) + A[7];
                        float s5 = fmaf(m5, A[3], A[4]) + A[5];
                        float s3 = fmaf(m3, A[1], A[2]) + A[3];
                        float s1 = fmaf(m1, hs,   A[0]) + A[1];
                        A[7] = s7 * pD;  A[6] = (A[6] + A[5]) * pb;
                        A[5] = s5 * pC;  A[4] = (A[4] + A[3]) * pb;
                        A[3] = s3 * pB;  A[2] = (A[2] + A[1]) * pb;
                        A[1] = s1 * pA;  A[0] = (A[0] + hs)   * pb;
                    } else {
                        // q[s] = p[s]*beta[s]; beta'[s] = q[s] + q[s+1] + skip*q[s+2]
                        float q0 = A[0] * pb, q1 = A[1] * pA;
                        float q2 = A[2] * pb, q3 = A[3] * pB;
                        float q4 = A[4] * pb, q5 = A[5] * pC;
                        float q6 = A[6] * pb, q7 = A[7] * pD;
                        float nq0 = dpp_shl1_f(q0) * dscale;           // q0 of lane i+1
                        float nq1 = dpp_shl1_f(q1) * dscale;           // q1 of lane i+1
                        A[0] = q0 + q1;
                        A[1] = fmaf(m3, q3, q1 + q2);                  // skip gate tg[4i+1]!=tg[4i]
                        A[2] = q2 + q3;
                        A[3] = fmaf(m5, q5, q3 + q4);
                        A[4] = q4 + q5;
                        A[5] = fmaf(m7, q7, q5 + q6);
                        A[6] = q6 + q7;
                        A[7] = fmaf(n7, nq1, q7 + nq0);                // gate tg[4i+4]!=tg[4i+3]
                    }
                }
                if ((u & 1) == 0) {   // stage steps t0+32+u, t0+33+u into other buffer
                    const int rA = ROWOF(t0 + 32 + u), rB = ROWOF(t0 + 33 + u);
                    dma16(po_b + (size_t)(hi ? rB : rA) * VSZ + 8 * lhalf,
                          rnxt + (size_t)u * VSZ);
                }
                if ((u & 3) == 3) {   // renorm (identical numerics to v8)
                    float lmx = fmaxf(fmaxf(fmaxf(A[0], A[1]), fmaxf(A[2], A[3])),
                                      fmaxf(fmaxf(A[4], A[5]), fmaxf(A[6], A[7])));
                    unsigned mb = __float_as_uint(lmx) >> 23;
                    mb = mb > 253u ? 253u : mb;
                    float sc_ = uifu((254u - mb) << 23);
                    A[0] *= sc_; A[1] *= sc_; A[2] *= sc_; A[3] *= sc_;
                    A[4] *= sc_; A[5] *= sc_; A[6] *= sc_; A[7] *= sc_;
                    E += (int)mb - 127;
                    int he = W ? dpp_shl1_i(E) : dpp_shr1_i(E);        // neighbor E (boundary lane: dscale unused)
                    int d  = min(max(he - E, -100), 100);
                    dscale = uifu((unsigned)(d + 127) << 23);
                }
            }
        }
        pbv = pn;
        unsigned short* tmp = rcur; rcur = rnxt; rnxt = tmp;
        t0 += 32;
    }
#undef ROWOF
}

__global__ __launch_bounds__(128, 1) void ctc_scan9(const unsigned short* __restrict__ po,
                                                    const float* __restrict__ pbf,
                                                    const int* __restrict__ targets,
                                                    const int* __restrict__ llen_p,
                                                    const int* __restrict__ tlen_p,
                                                    float* __restrict__ out,
                                                    int T, int S) {
    const int b   = blockIdx.x;
    const int w   = threadIdx.x >> 6;     // 0 = forward wave, 1 = backward wave
    const int i   = threadIdx.x & 63;
    const int len  = llen_p[b];
    const int lm1  = len - 1;
    const int lenF = (len + 1) >> 1;      // forward steps m
    const int lenD = w ? (len - lenF) : lenF;

    __shared__ __align__(16) unsigned short rows[2][2][32][VSZ];  // [wave][dbuf][slot][vocab]
    __shared__ __align__(16) float bfin[512];
    __shared__ int bein[64];

    // skip masks from targets (j0 = 4i covers odd states 8i+1,+3,+5,+7)
    const int* tg  = targets + (size_t)b * S;
    const int Sm1  = S - 1;
    const int j0   = 4 * i;
    const int tm   = tg[max(min(j0 - 1, Sm1), 0)];
    const int t0l  = tg[min(j0,     Sm1)];
    const int t1l  = tg[min(j0 + 1, Sm1)];
    const int t2l  = tg[min(j0 + 2, Sm1)];
    const int t3l  = tg[min(j0 + 3, Sm1)];
    const int t4l  = tg[min(j0 + 4, Sm1)];
    const float m1 = (j0 == 0 || t0l != tm) ? 1.f : 0.f;
    const float m3 = (t1l != t0l) ? 1.f : 0.f;
    const float m5 = (t2l != t1l) ? 1.f : 0.f;
    const float m7 = (t3l != t2l) ? 1.f : 0.f;
    const float n7 = (t4l != t3l) ? 1.f : 0.f;   // backward-only boundary gate

    const unsigned short* po_b = po + (size_t)b * T * VSZ;
    const float*          pbr  = pbf + (size_t)b * T;

    float A[8];
    int   E = 0;
    if (w == 0) {
        #pragma unroll
        for (int k = 0; k < 8; ++k) A[k] = 0.f;
        if (i == 0) A[0] = 1.f;                               // alpha init: onehot state 0
        scan_dir<0>(po_b, pbr, &rows[0][0][0][0], &rows[0][1][0][0],
                    lenD, lm1, i, m1, m3, m5, m7, n7, A, E);
    } else {
        const int tl = tlen_p[b];
        const int s1 = 2 * tl - 1, s2 = 2 * tl;               // final states
        #pragma unroll
        for (int k = 0; k < 8; ++k)
            A[k] = (8 * i + k == s1 || 8 * i + k == s2) ? 1.f : 0.f;   // beta_{len-1}
        scan_dir<1>(po_b, pbr, &rows[1][0][0][0], &rows[1][1][0][0],
                    lenD, lm1, i, m1, m3, m5, m7, n7, A, E);
        *(float4*)&bfin[8 * i]     = make_float4(A[0], A[1], A[2], A[3]);
        *(float4*)&bfin[8 * i + 4] = make_float4(A[4], A[5], A[6], A[7]);
        bein[i] = E;
    }
    __syncthreads();
    if (w == 0) {
        // total = sum_s alpha_{m-1}[s] * beta_{m-1}[s], with per-lane pow2 exponents
        float4 u0 = *(float4*)&bfin[8 * i];
        float4 u1 = *(float4*)&bfin[8 * i + 4];
        float dsum = A[0]*u0.x + A[1]*u0.y + A[2]*u0.z + A[3]*u0.w
                   + A[4]*u1.x + A[5]*u1.y + A[6]*u1.z + A[7]*u1.w;
        float li = (dsum > 0.f) ? __logf(dsum) + (float)(E + bein[i]) * LN2F : NEG;
        float mx = li;
        #pragma unroll
        for (int off = 32; off; off >>= 1) mx = fmaxf(mx, __shfl_xor(mx, off, 64));
        float ss = __expf(li - mx);
        #pragma unroll
        for (int off = 32; off; off >>= 1) ss += __shfl_xor(ss, off, 64);
        if (i == 0) out[b] = -(mx + __logf(ss));
    }
}

// ---------------------------------------------------------------------------
// Fallback (R2, known-good) if workspace is too small.
// ---------------------------------------------------------------------------
__device__ __forceinline__ void barrier_lgkm() {
    __asm__ volatile("s_waitcnt lgkmcnt(0)\n\ts_barrier" ::: "memory");
}

__global__ __launch_bounds__(256) void lse_kernel(const float* __restrict__ logits,
                                                  float* __restrict__ lse,
                                                  int nrows) {
    int row = blockIdx.x * 4 + (threadIdx.x >> 6);
    if (row >= nrows) return;
    int lane = threadIdx.x & 63;
    const float4* p = (const float4*)(logits + (size_t)row * VSZ);
    float4 x = p[lane];
    float m = fmaxf(fmaxf(x.x, x.y), fmaxf(x.z, x.w));
    #pragma unroll
    for (int off = 32; off; off >>= 1) m = fmaxf(m, __shfl_xor(m, off, 64));
    float s = __expf(x.x - m) + __expf(x.y - m) + __expf(x.z - m) + __expf(x.w - m);
    #pragma unroll
    for (int off = 32; off; off >>= 1) s += __shfl_xor(s, off, 64);
    if (lane == 0) lse[row] = m + __logf(s);
}

__device__ __forceinline__ float lae(float a, float b) {
    float mx = fmaxf(a, b);
    float mn = fminf(a, b);
    return mx + __logf(1.0f + __expf(mn - mx));
}

__global__ __launch_bounds__(256, 1) void ctc_scan_fb(const float* __restrict__ logits,
                                                      const int* __restrict__ targets,
                                                      const int* __restrict__ llen_p,
                                                      const int* __restrict__ tlen_p,
                                                      const float* __restrict__ lse,
                                                      float* __restrict__ out,
                                                      int T, int S) {
    const int b = blockIdx.x;
    const int i = threadIdx.x;
    const int len = llen_p[b];

    __shared__ float blankv[TCAP];
    __shared__ float abuf[2][256 + 2];
    __shared__ float wsum[4];

    const float* __restrict__ lgb  = logits + (size_t)b * T * VSZ;
    const float* __restrict__ lseb = lse + (size_t)b * T;

    int  lab  = 0;
    bool skip = false;
    if (i < S) {
        lab = targets[b * S + i];
        int prev = (i >= 1) ? targets[b * S + i - 1] : -1;
        skip = (lab != prev);
    }
    for (int t = i; t < len; t += 256) blankv[t] = lgb[(size_t)t * VSZ];
    if (i < 2) abuf[i][0] = NEG;
    __syncthreads();

    float aEven = (i == 0) ? 0.0f : NEG;
    float aOdd  = NEG;
    const int lm1 = len - 1;
    float v0 = lgb[(size_t)lab];
    float v1 = lgb[(size_t)min(1, lm1) * VSZ + lab];
    float v2 = lgb[(size_t)min(2, lm1) * VSZ + lab];

    for (int t = 0; t < len; ++t) {
        float v3 = lgb[(size_t)min(t + 3, lm1) * VSZ + lab];
        float blv = blankv[t];
        abuf[t & 1][i + 1] = aOdd;
        barrier_lgkm();
        float nb = abuf[t & 1][i];
        float ne = lae(aEven, nb) + blv;
        float no = lae(lae(aOdd, aEven), skip ? nb : NEG) + v0;
        aEven = ne; aOdd = no;
        v0 = v1; v1 = v2; v2 = v3;
    }

    blankv[2 * i]     = aEven;
    blankv[2 * i + 1] = aOdd;
    float part = 0.f;
    for (int t = i; t < len; t += 256) part += lseb[t];
    #pragma unroll
    for (int off = 32; off; off >>= 1) part += __shfl_xor(part, off, 64);
    if ((i & 63) == 0) wsum[i >> 6] = part;
    __syncthreads();
    if (i == 0) {
        int tl = tlen_p[b];
        float s = wsum[0] + wsum[1] + wsum[2] + wsum[3];
        out[b] = s - lae(blankv[2 * tl - 1], blankv[2 * tl]);
    }
}

// ---------------------------------------------------------------------------
extern "C" void kernel_launch(void* const* d_in, const int* in_sizes, int n_in,
                              void* d_out, int out_size, void* d_ws, size_t ws_size,
                              hipStream_t stream) {
    const float* logits  = (const float*)d_in[0];
    const int*   targets = (const int*)d_in[1];
    const int*   llen    = (const int*)d_in[2];
    const int*   tlen    = (const int*)d_in[3];
    float*       out     = (float*)d_out;

    const int B = in_sizes[2];
    const int S = in_sizes[1] / B;
    const int T = in_sizes[0] / (B * VSZ);
    const int nrows = B * T;

    const size_t need = (size_t)nrows * VSZ * sizeof(unsigned short)
                      + (size_t)nrows * sizeof(float);
    if (ws_size >= need) {
        unsigned short* po = (unsigned short*)d_ws;            // nrows*256 bf16
        float* pbf = (float*)(po + (size_t)nrows * VSZ);       // nrows f32
        dim3 grid((T + 3) / 4, B);
        prep6<<<grid, 256, 0, stream>>>(logits, targets, po, pbf, T, S);
        ctc_scan9<<<B, 128, 0, stream>>>(po, pbf, targets, llen, tlen, out, T, S);
    } else {
        float* lse = (float*)d_ws;                             // nrows f32
        lse_kernel<<<(nrows + 3) / 4, 256, 0, stream>>>(logits, lse, nrows);
        ctc_scan_fb<<<B, 256, 0, stream>>>(logits, targets, llen, tlen, lse, out, T, S);
    }
}